// Round 13
// baseline (757.192 us; speedup 1.0000x reference)
//
#include <hip/hip_runtime.h>
#include <math.h>

#define B    4
#define T    16384
#define A    256
#define K    256
#define PAD  128
#define TP   (T + 2*PAD)      // 16640
#define TOUT (TP - K + 1)     // 16385
#define ITERS 16
#define CHUNK 512
#define NCHUNK 33
#define NCP  36
#define TILE 2048
#define NTILE 9
#define NBB  128              // iter blocks per batch (atom pairs)
#define NITB (NBB*B)          // 512 iteration blocks

#define TAP(acc, s0,s1,s2,s3, dq) { acc = fmaf(s0,(dq).x,acc); acc = fmaf(s1,(dq).y,acc); \
                                    acc = fmaf(s2,(dq).z,acc); acc = fmaf(s3,(dq).w,acc); }

struct __align__(16) SmemIt {
    float rp[1304];           // 324 staged quads (1296) + pad
    float dn[2*K];            // own two atoms (persists across iterations in coop)
    float sel[K];             // picked atom
    float wv[16]; int wi[16];
    float fv; int fi;
};

__device__ __forceinline__ void wave_amax(float& bv, int& bi) {
    #pragma unroll
    for (int off = 32; off; off >>= 1) {
        float ov = __shfl_down(bv, off);
        int   oi = __shfl_down(bi, off);
        if (ov > bv || (ov == bv && oi < bi)) { bv = ov; bi = oi; }
    }
}

// Per-batch grid barrier. Safe only under cooperative launch.
__device__ __forceinline__ void gbar(unsigned* c, unsigned target) {
    __syncthreads();
    if (threadIdx.x == 0) {
        __hip_atomic_fetch_add(c, 1u, __ATOMIC_RELEASE, __HIP_MEMORY_SCOPE_AGENT);
        while (__hip_atomic_load(c, __ATOMIC_ACQUIRE, __HIP_MEMORY_SCOPE_AGENT) < target)
            __builtin_amdgcn_s_sleep(2);
    }
    __syncthreads();
}

// ---------------- norm + init (ordinary launch, grid A) ----------------
__global__ __launch_bounds__(256) void k_norm_init(const float* __restrict__ x,
        const float* __restrict__ d, float* __restrict__ dn,
        float* __restrict__ rp, float* __restrict__ recon) {
    __shared__ float ls[4];
    int a = blockIdx.x, tid = threadIdx.x;
    int lane = tid & 63, w = tid >> 6;
    float v = d[a*K + tid];
    float sq = v*v;
    #pragma unroll
    for (int off = 32; off; off >>= 1) sq += __shfl_down(sq, off);
    if (lane == 0) ls[w] = sq;
    __syncthreads();
    float norm = sqrtf(ls[0] + ls[1] + ls[2] + ls[3]) + 1e-12f;
    dn[a*K + tid] = v / norm;
    for (int i = blockIdx.x*256 + tid; i < B*TP; i += A*256) {
        int bb = i / TP, t = i - bb*TP;
        float xv = (t >= PAD && t < PAD + T) ? x[bb*T + (t - PAD)] : 0.f;
        rp[i] = xv;
        recon[i] = 0.f;
    }
}

// ---------------- full conv: NA=4 atoms, G=2 output streams per block -------------
// grid (9, 64, 4). Per kq: 6 LDS b128 (4 dict uniform + 2 rp) : 128 FMA-instr —
// LDS 576 cyc vs VALU 512 cyc per CU (balanced; NA=2 was 1.5x LDS-bound).
// launch_bounds(256,2): allocator law (R5/R6/R9/R11): VGPR cap ~256/arg2.
__global__ __launch_bounds__(256, 2) void k_conv(const float* __restrict__ rp,
        const float* __restrict__ dn,
        float* __restrict__ segval, int* __restrict__ segidx) {
    __shared__ float s_rp[2336];
    __shared__ float s_dn[4*K];
    __shared__ float wv[32]; __shared__ int wi[32];
    const int tid = threadIdx.x, lane = tid & 63, w = tid >> 6;
    const int a0 = blockIdx.y, b = blockIdx.z;      // a0: atom quad 0..63
    const int aA = a0*4;
    const int t0 = blockIdx.x * TILE;
    for (int i = tid; i < 4*K; i += 256) s_dn[i] = dn[aA*K + i];
    const float4* rp4 = (const float4*)(rp + (size_t)b*TP);
    float4* s4 = (float4*)s_rp;
    for (int i = tid; i < 580; i += 256) {
        int g = t0/4 + i;
        float4 v = {0.f,0.f,0.f,0.f};
        if (g*4 < TP) v = rp4[g];
        s4[i] = v;
    }
    __syncthreads();
    const float4* srp4 = (const float4*)s_rp;
    const float4* d4 = (const float4*)s_dn;         // atom s quad kq at s*64+kq
    float acc[4][2][4];
    #pragma unroll
    for (int s = 0; s < 4; s++)
        #pragma unroll
        for (int g = 0; g < 2; g++)
            #pragma unroll
            for (int j = 0; j < 4; j++) acc[s][g][j] = 0.f;
    float4 p = srp4[tid], q = srp4[tid + 256];
    #pragma unroll 2
    for (int kq = 0; kq < 64; kq++) {
        float4 pn = srp4[tid + kq + 1];
        float4 qn = srp4[tid + 256 + kq + 1];
        #pragma unroll
        for (int s = 0; s < 4; s++) {
            float4 dq = d4[s*64 + kq];
            TAP(acc[s][0][0], p.x,p.y,p.z,p.w, dq); TAP(acc[s][0][1], p.y,p.z,p.w,pn.x, dq);
            TAP(acc[s][0][2], p.z,p.w,pn.x,pn.y, dq); TAP(acc[s][0][3], p.w,pn.x,pn.y,pn.z, dq);
            TAP(acc[s][1][0], q.x,q.y,q.z,q.w, dq); TAP(acc[s][1][1], q.y,q.z,q.w,qn.x, dq);
            TAP(acc[s][1][2], q.z,q.w,qn.x,qn.y, dq); TAP(acc[s][1][3], q.w,qn.x,qn.y,qn.z, dq);
        }
        p = pn; q = qn;
    }
    const int lt = tid * 4;
    #pragma unroll
    for (int s = 0; s < 4; s++) {
        #pragma unroll
        for (int g = 0; g < 2; g++) {
            float bv = -INFINITY; int bi = 0x7fffffff;
            #pragma unroll
            for (int j = 0; j < 4; j++) {
                int t = t0 + g*1024 + lt + j;
                if (t < TOUT && acc[s][g][j] > bv) { bv = acc[s][g][j]; bi = (aA+s)*TOUT + t; }
            }
            wave_amax(bv, bi);
            if (lane == 0) { wv[s*8 + g*4 + w] = bv; wi[s*8 + g*4 + w] = bi; }
        }
    }
    __syncthreads();
    if (tid < 16) {     // (s = tid>>2, c = tid&3): partials s*8 + (c>>1)*4 + (c&1)*2
        int s = tid >> 2, c = tid & 3;
        int base = s*8 + (c >> 1)*4 + (c & 1)*2;
        float v0 = wv[base];   int i0 = wi[base];
        float v1 = wv[base+1]; int i1 = wi[base+1];
        if (v1 > v0 || (v1 == v0 && i1 < i0)) { v0 = v1; i0 = i1; }
        int chunk = blockIdx.x*4 + c;
        if (chunk < NCHUNK) {
            segval[((size_t)b*A + aA + s)*NCP + chunk] = v0;
            segidx[((size_t)b*A + aA + s)*NCP + chunk] = i0;
        }
    }
}

// ---------------- one matching-pursuit iteration (shared coop/fallback) ----------------
__device__ __forceinline__ void dev_iter2(int a0, int b, int tid, int last, int load_dn,
        const float* __restrict__ avc, const int* __restrict__ aic,
        float* __restrict__ avn, int* __restrict__ ain,
        const float* __restrict__ rin, float* __restrict__ rout,
        float* __restrict__ recon, const float* __restrict__ dn,
        float* __restrict__ segval, int* __restrict__ segidx, SmemIt& sm) {
    const int aA = a0*2;
    const int lane = tid & 63, w = tid >> 6;
    // pick (redundant, deterministic across blocks of same b)
    {
        float bv = avc[b*A + tid]; int bi = aic[b*A + tid];
        wave_amax(bv, bi);
        if (lane == 0) { sm.wv[w] = bv; sm.wi[w] = bi; }
        __syncthreads();
        if (tid == 0) {
            bv = sm.wv[0]; bi = sm.wi[0];
            for (int j = 1; j < 4; j++)
                if (sm.wv[j] > bv || (sm.wv[j] == bv && sm.wi[j] < bi)) { bv = sm.wv[j]; bi = sm.wi[j]; }
            sm.fv = bv; sm.fi = bi;
        }
        __syncthreads();
    }
    float val = sm.fv; int idx = sm.fi;
    int atom = idx / TOUT, pos = idx - atom*TOUT;
    sm.sel[tid] = dn[atom*K + tid];
    if (load_dn) {                       // dn is iteration-invariant: coop loads once
        sm.dn[tid] = dn[aA*K + tid];
        sm.dn[256 + tid] = dn[aA*K + 256 + tid];
    }

    int lo = pos - (K-1); if (lo < 0) lo = 0;
    int c_lo = lo >> 9;
    int tbase = c_lo * CHUNK;

    if (!last) {   // stage 2 chunks + K halo (324 quads)
        const float4* rin4 = (const float4*)(rin + (size_t)b*TP);
        float4* s4 = (float4*)sm.rp;
        for (int i = tid; i < 324; i += 256) {
            int g = tbase/4 + i;
            float4 v = {0.f,0.f,0.f,0.f};
            if (g*4 < TP) v = rin4[g];
            s4[i] = v;
        }
    }
    __syncthreads();
    if (!last) {   // distributed rp copy+update (blocks a0=0..16, 1 quad/thread)
        const float4* rin4 = (const float4*)(rin + (size_t)b*TP);
        float4* rout4 = (float4*)(rout + (size_t)b*TP);
        int i = a0*256 + tid;
        if (i < TP/4) {
            float4 v = rin4[i];
            int o = i*4 - pos;
            if (o > -4 && o < K) {
                if (o+0 >= 0 && o+0 < K) v.x -= val * sm.sel[o+0];
                if (o+1 >= 0 && o+1 < K) v.y -= val * sm.sel[o+1];
                if (o+2 >= 0 && o+2 < K) v.z -= val * sm.sel[o+2];
                if (o+3 >= 0 && o+3 < K) v.w -= val * sm.sel[o+3];
            }
            rout4[i] = v;
        }
    }
    if (a0 == 0) recon[(size_t)b*TP + pos + tid] += val * sm.sel[tid];
    if (last) return;

    sm.rp[pos - tbase + tid] -= val * sm.sel[tid];
    __syncthreads();

    // recompute 1024 outputs [tbase, tbase+1024) for both atoms (conv-identical chain)
    const float4* srp4 = (const float4*)sm.rp;
    const float4* dA4 = (const float4*)sm.dn;
    const float4* dB4 = dA4 + 64;
    float cA[4] = {0,0,0,0}, cB[4] = {0,0,0,0};
    float4 p = srp4[tid];
    #pragma unroll 4
    for (int kq = 0; kq < 64; kq++) {
        float4 pn = srp4[tid + kq + 1];
        float4 dA = dA4[kq], dB = dB4[kq];
        TAP(cA[0], p.x,p.y,p.z,p.w, dA); TAP(cA[1], p.y,p.z,p.w,pn.x, dA);
        TAP(cA[2], p.z,p.w,pn.x,pn.y, dA); TAP(cA[3], p.w,pn.x,pn.y,pn.z, dA);
        TAP(cB[0], p.x,p.y,p.z,p.w, dB); TAP(cB[1], p.y,p.z,p.w,pn.x, dB);
        TAP(cB[2], p.z,p.w,pn.x,pn.y, dB); TAP(cB[3], p.w,pn.x,pn.y,pn.z, dB);
        p = pn;
    }
    const int lt = tid * 4;
    float bvA = -INFINITY, bvB = -INFINITY;
    int biA = 0x7fffffff, biB = 0x7fffffff;
    #pragma unroll
    for (int j = 0; j < 4; j++) {
        int t = tbase + lt + j;
        if (t < TOUT) {
            if (cA[j] > bvA) { bvA = cA[j]; biA = aA*TOUT + t; }
            if (cB[j] > bvB) { bvB = cB[j]; biB = (aA+1)*TOUT + t; }
        }
    }
    wave_amax(bvA, biA); wave_amax(bvB, biB);
    if (lane == 0) { sm.wv[w] = bvA; sm.wi[w] = biA; sm.wv[8+w] = bvB; sm.wi[8+w] = biB; }
    __syncthreads();
    if (tid < 4) {     // (s = tid>>1, c = tid&1): partials s*8 + c*2 + {0,1}
        int s = tid >> 1, c = tid & 1;
        int base = s*8 + c*2;
        float v0 = sm.wv[base];   int i0 = sm.wi[base];
        float v1 = sm.wv[base+1]; int i1 = sm.wi[base+1];
        if (v1 > v0 || (v1 == v0 && i1 < i0)) { v0 = v1; i0 = i1; }
        int chunk = c_lo + c;
        if (chunk < NCHUNK) {
            segval[((size_t)b*A + aA + s)*NCP + chunk] = v0;
            segidx[((size_t)b*A + aA + s)*NCP + chunk] = i0;
        }
    }
    __syncthreads();
    if (w < 2) {   // refresh per-atom best over all chunks
        int at = aA + w;
        float bv = -INFINITY; int bi = 0x7fffffff;
        if (lane < NCHUNK) {
            bv = segval[((size_t)b*A + at)*NCP + lane];
            bi = segidx[((size_t)b*A + at)*NCP + lane];
        }
        wave_amax(bv, bi);
        if (lane == 0) { avn[b*A + at] = bv; ain[b*A + at] = bi; }
    }
}

// ---------------- cooperative iteration kernel, XCD-pinned batches ----------------
// Heuristic: bid -> XCD is round-robin (bid & 7). Map batch b to XCDs {2b, 2b+1}
// so each batch's pick array / rin / barrier counter stay in 2 L2s. Correctness
// does not depend on the mapping (any bid->(b,a0) bijection is valid).
__global__ void __launch_bounds__(256, 2)
k_it(const float* __restrict__ dn, float* __restrict__ rp0, float* __restrict__ rp1,
     float* __restrict__ recon, float* __restrict__ segval, int* __restrict__ segidx,
     float* __restrict__ abv0, int* __restrict__ abi0,
     float* __restrict__ abv1, int* __restrict__ abi1,
     float* __restrict__ out, unsigned* __restrict__ bar) {
    __shared__ SmemIt sm;
    const int bid = blockIdx.x, tid = threadIdx.x;
    const int b  = (bid & 7) >> 1;
    const int a0 = ((bid >> 3) << 1) | (bid & 1);    // 0..127, bijective per b
    const int lane = tid & 63, w = tid >> 6;
    unsigned* bar_b = bar + b*256;
    unsigned gen = 0;
    // phase 0: per-atom best from conv's segval (own atoms only)
    if (w < 2) {
        int atom = a0*2 + w;
        float bv = -INFINITY; int bi = 0x7fffffff;
        if (lane < NCHUNK) {
            bv = segval[((size_t)b*A + atom)*NCP + lane];
            bi = segidx[((size_t)b*A + atom)*NCP + lane];
        }
        wave_amax(bv, bi);
        if (lane == 0) { abv0[b*A + atom] = bv; abi0[b*A + atom] = bi; }
    }
    gen++; gbar(bar_b, gen*NBB);
    const float* rin = rp0; float* rout = rp1;
    const float* avc = abv0; const int* aic = abi0;
    float* avn = abv1; int* ain = abi1;
    for (int it = 0; it < ITERS; it++) {
        dev_iter2(a0, b, tid, it == ITERS-1, it == 0, avc, aic, avn, ain,
                  rin, rout, recon, dn, segval, segidx, sm);
        { const float* t1 = rin; rin = rout; rout = (float*)t1; }
        { const float* t2 = avc; avc = avn; avn = (float*)t2; }
        { const int*   t3 = aic; aic = ain; ain = (int*)t3; }
        gen++; gbar(bar_b, gen*NBB);
    }
    for (int i = a0*256 + tid; i < T; i += NBB*256)
        out[b*T + i] = recon[(size_t)b*TP + PAD + i];
}

// ---------------- non-cooperative fallback ----------------
__global__ void k_f_abest(const float* __restrict__ segval, const int* __restrict__ segidx,
                          float* __restrict__ abv, int* __restrict__ abi) {
    int b = blockIdx.x, a = threadIdx.x;
    float bv = -INFINITY; int bi = 0x7fffffff;
    for (int c = 0; c < NCHUNK; c++) {
        float v = segval[((size_t)b*A + a)*NCP + c];
        int  ix = segidx[((size_t)b*A + a)*NCP + c];
        if (v > bv || (v == bv && ix < bi)) { bv = v; bi = ix; }
    }
    abv[b*A + a] = bv; abi[b*A + a] = bi;
}
__global__ void __launch_bounds__(256, 2) k_f_iter(int last,
        const float* avc, const int* aic, float* avn, int* ain,
        const float* rin, float* rout, float* recon, const float* dn,
        float* segval, int* segidx) {
    __shared__ SmemIt sm;
    int bid = blockIdx.x;
    dev_iter2(((bid >> 3) << 1) | (bid & 1), (bid & 7) >> 1, threadIdx.x, last, 1,
              avc, aic, avn, ain, rin, rout, recon, dn, segval, segidx, sm);
}
__global__ void k_f_out(const float* __restrict__ recon, float* __restrict__ out) {
    int i = blockIdx.x * blockDim.x + threadIdx.x;
    if (i >= B*T) return;
    int b = i / T, t = i - b*T;
    out[i] = recon[(size_t)b*TP + PAD + t];
}

extern "C" void kernel_launch(void* const* d_in, const int* in_sizes, int n_in,
                              void* d_out, int out_size, void* d_ws, size_t ws_size,
                              hipStream_t stream) {
    const float* x = (const float*)d_in[0];
    const float* d = (const float*)d_in[1];
    float* out = (float*)d_out;

    float* ws     = (float*)d_ws;
    float* dn     = ws;                                   // A*K
    float* rp0    = dn  + (size_t)A*K;                    // B*TP
    float* rp1    = rp0 + (size_t)B*TP;                   // B*TP
    float* recon  = rp1 + (size_t)B*TP;                   // B*TP
    float* segval = recon + (size_t)B*TP;                 // B*A*NCP
    int*   segidx = (int*)(segval + (size_t)B*A*NCP);     // B*A*NCP
    float* abv0   = (float*)(segidx + (size_t)B*A*NCP);   // B*A
    float* abv1   = abv0 + (size_t)B*A;                   // B*A
    int*   abi0   = (int*)(abv1 + (size_t)B*A);           // B*A
    int*   abi1   = abi0 + (size_t)B*A;                   // B*A
    unsigned* bar = (unsigned*)(abi1 + (size_t)B*A);      // 4 per-batch counters, 1 KB apart

    // phase 1+2: ordinary launches — big grids, no co-residency constraint
    k_norm_init<<<A, 256, 0, stream>>>(x, d, dn, rp0, recon);
    k_conv<<<dim3(NTILE, A/4, B), 256, 0, stream>>>(rp0, dn, segval, segidx);

    // phase 3: cooperative iterations (512x256, R8-proven shape)
    int nb = 0, ncu = 0;
    hipError_t e1 = hipOccupancyMaxActiveBlocksPerMultiprocessor(&nb, (const void*)k_it, 256, 0);
    hipError_t e2 = hipDeviceGetAttribute(&ncu, hipDeviceAttributeMultiprocessorCount, 0);
    if (e1 == hipSuccess && e2 == hipSuccess && (long)nb * ncu >= NITB) {
        hipMemsetAsync(bar, 0, 4*256*sizeof(unsigned), stream);
        void* args[] = {(void*)&dn, (void*)&rp0, (void*)&rp1, (void*)&recon,
                        (void*)&segval, (void*)&segidx,
                        (void*)&abv0, (void*)&abi0, (void*)&abv1, (void*)&abi1,
                        (void*)&out, (void*)&bar};
        if (hipLaunchCooperativeKernel((const void*)k_it, dim3(NITB), dim3(256),
                                       args, 0, stream) == hipSuccess)
            return;
    }
    // fallback: non-cooperative, double-buffered, race-free
    k_f_abest<<<B, 256, 0, stream>>>(segval, segidx, abv0, abi0);
    float* rbuf[2] = {rp0, rp1};
    float* av[2]   = {abv0, abv1};
    int*   ai[2]   = {abi0, abi1};
    for (int it = 0; it < ITERS; it++) {
        k_f_iter<<<NITB, 256, 0, stream>>>(it == ITERS-1 ? 1 : 0,
                                           av[it & 1], ai[it & 1],
                                           av[(it + 1) & 1], ai[(it + 1) & 1],
                                           rbuf[it & 1], rbuf[(it + 1) & 1],
                                           recon, dn, segval, segidx);
    }
    k_f_out<<<(B*T + 255)/256, 256, 0, stream>>>(recon, out);
}